// Round 15
// baseline (229.188 us; speedup 1.0000x reference)
//
#include <hip/hip_runtime.h>
#include <stdint.h>

#define NB 200000
#define BB 4
#define GG 64
#define MAXPOS 128
#define BATCH 256
#define MPRE 16384                 // prefix length scanned by K1 (exactness checked in K2)
#define CHP 256                    // anchors per K1 block / per selection chunk
#define NCHP (MPRE / CHP)          // 64 chunks per image
#define REPS_K1 24
#define REPS_K2 12

// thresholds folded: inter - t*u >= 0  <=>  ((1+t)/t)*inter - (a1+ga) >= 0
#define CP (1.7f / 0.7f)
#define CN (1.3f / 0.3f)

// ---------------- K1: prefix-only flags + per-chunk counts; resets ticket ----------------
__global__ __launch_bounds__(256) void rpn_flags_kernel(
        const float* __restrict__ anchors, const float* __restrict__ gt,
        uint8_t* __restrict__ flags, uint32_t* __restrict__ chunkCnt,
        uint32_t* __restrict__ done) {
    int b = blockIdx.y;
    int tid = threadIdx.x, lane = tid & 63, wid = tid >> 6;
    // deterministic ticket init EVERY call (d_ws contents are never guaranteed)
    if (blockIdx.x == 0 && b == 0 && tid == 0) *done = 0u;
    __shared__ __align__(16) float4 sG[GG];
    if (tid < GG) sG[tid] = ((const float4*)gt)[b * GG + tid];
    __syncthreads();

    int i = blockIdx.x * CHP + tid;            // i < MPRE <= NB always
    float4 a = ((const float4*)anchors)[(size_t)b * NB + i];
    float na1 = -((a.z - a.x) * (a.w - a.y));
    float mp = -1.0f, mn = -1.0f;

    #pragma unroll 8
    for (int g = 0; g < GG; ++g) {
        float4 c = sG[g];                       // broadcast ds_read_b128
        float ga = (c.z - c.x) * (c.w - c.y);
        float w = fmaxf(fminf(a.z, c.z) - fmaxf(a.x, c.x), 0.0f);
        float h = fmaxf(fminf(a.w, c.w) - fmaxf(a.y, c.y), 0.0f);
        float inter = w * h;
        float s = na1 - ga;
        mp = fmaxf(mp, __builtin_fmaf(CP, inter, s));
        mn = fmaxf(mn, __builtin_fmaf(CN, inter, s));
    }

    bool p = (mp >= 0.0f);
    bool n = (mn < 0.0f);
    flags[(size_t)b * NB + i] = (uint8_t)((p ? 1 : 0) | (n ? 2 : 0));

    uint32_t pn = (p ? 1u : 0u) + (n ? 0x10000u : 0u);
    for (int off = 32; off > 0; off >>= 1) pn += __shfl_down(pn, off);
    __shared__ uint32_t wSum[4];
    if (lane == 0) wSum[wid] = pn;
    __syncthreads();
    if (tid == 0)
        chunkCnt[b * NCHP + blockIdx.x] = wSum[0] + wSum[1] + wSum[2] + wSum[3];
}

// ---------------- K2: prefix scan + selection + loss + ticket finalize ----------------
__global__ __launch_bounds__(1024) void rpn_select_kernel(
        const uint8_t* __restrict__ flags,
        const float* __restrict__ logits, const float* __restrict__ breg,
        const float* __restrict__ anchors, const float* __restrict__ gt,
        const uint32_t* __restrict__ chunkCnt,
        float* __restrict__ partial, uint32_t* __restrict__ done,
        float* __restrict__ out) {
    int b = blockIdx.x;
    const uint8_t* __restrict__ F = flags + (size_t)b * NB;
    __shared__ __align__(16) float4 sG[GG];
    __shared__ int basP[NCHP], basN[NCHP];
    __shared__ int sTotP, sTotN, sNumPos, sNumNeg;
    __shared__ int selPos[MAXPOS];
    __shared__ int selNeg[BATCH];
    __shared__ float sB, sS;
    __shared__ uint32_t ticket;
    int tid = threadIdx.x, lane = tid & 63, wid = tid >> 6;

    if (tid < GG) sG[tid] = ((const float4*)gt)[b * GG + tid];
    if (tid == 0) { sB = 0.0f; sS = 0.0f; }

    if (wid == 0) {
        unsigned long long e = 0ULL;
        if (lane < NCHP) {
            uint32_t c = chunkCnt[b * NCHP + lane];
            e = (unsigned long long)(c & 0xFFFFu) | ((unsigned long long)(c >> 16) << 32);
        }
        unsigned long long inc = e;
        for (int off = 1; off < 64; off <<= 1) {
            unsigned long long v = __shfl_up(inc, off);
            if (lane >= off) inc += v;
        }
        if (lane < NCHP) {
            unsigned long long ex = inc - e;
            basP[lane] = (int)(ex & 0xFFFFFFFFULL);
            basN[lane] = (int)(ex >> 32);
        }
        unsigned long long tot = __shfl(inc, 63);
        if (lane == 0) {
            sTotP = (int)(tot & 0xFFFFFFFFULL);
            sTotN = (int)(tot >> 32);
        }
    }
    __syncthreads();

    bool fast = (sTotP >= MAXPOS) && (sTotN >= BATCH - MAXPOS);
    int numPos, numNeg;

    if (fast) {
        numPos = MAXPOS; numNeg = BATCH - MAXPOS;
        for (int c = wid; c < NCHP; c += 16) {
            int bp = basP[c], bn = basN[c];
            if (bp >= numPos && bn >= numNeg) break;
            int offP = 0, offN = 0;
            #pragma unroll
            for (int s = 0; s < CHP / 64; ++s) {
                int idx = c * CHP + s * 64 + lane;
                uint8_t f = F[idx];
                bool p = (f & 1) != 0, n = (f & 2) != 0;
                unsigned long long mpm = __ballot(p), mnm = __ballot(n);
                unsigned long long lt = (1ULL << lane) - 1ULL;
                int rp = bp + offP + __popcll(mpm & lt);
                int rn = bn + offN + __popcll(mnm & lt);
                if (p && rp < numPos) selPos[rp] = idx;
                if (n && rn < numNeg) selNeg[rn] = idx;
                offP += __popcll(mpm); offN += __popcll(mnm);
            }
        }
    } else {
        if (wid == 0) {
            int totP = 0, totN = 0;
            for (int g0 = 0; g0 < NB; g0 += 64) {
                int idx = g0 + lane;
                bool p = false, n = false;
                if (idx < NB) {
                    if (idx < MPRE) {
                        uint8_t f = F[idx];
                        p = (f & 1) != 0; n = (f & 2) != 0;
                    } else {
                        float4 a = ((const float4*)anchors)[(size_t)b * NB + idx];
                        float na1 = -((a.z - a.x) * (a.w - a.y));
                        float mp = -1.0f, mn = -1.0f;
                        for (int g = 0; g < GG; ++g) {
                            float4 c = sG[g];
                            float ga = (c.z - c.x) * (c.w - c.y);
                            float w = fmaxf(fminf(a.z, c.z) - fmaxf(a.x, c.x), 0.0f);
                            float h = fmaxf(fminf(a.w, c.w) - fmaxf(a.y, c.y), 0.0f);
                            float inter = w * h;
                            float s = na1 - ga;
                            mp = fmaxf(mp, __builtin_fmaf(CP, inter, s));
                            mn = fmaxf(mn, __builtin_fmaf(CN, inter, s));
                        }
                        p = (mp >= 0.0f); n = (mn < 0.0f);
                    }
                }
                unsigned long long mpm = __ballot(p), mnm = __ballot(n);
                unsigned long long lt = (1ULL << lane) - 1ULL;
                int rp = totP + __popcll(mpm & lt);
                int rn = totN + __popcll(mnm & lt);
                if (p && rp < MAXPOS) selPos[rp] = idx;
                if (n && rn < BATCH) selNeg[rn] = idx;
                totP += __popcll(mpm); totN += __popcll(mnm);
                if (totP >= MAXPOS && totN >= BATCH) break;
            }
            if (lane == 0) {
                int np = min(totP, MAXPOS);
                sNumPos = np;
                sNumNeg = min(totN, BATCH - np);
            }
        }
    }
    __syncthreads();
    if (!fast) { numPos = sNumPos; numNeg = sNumNeg; }

    float bce_acc = 0.0f, sl1_acc = 0.0f;
    for (int t = tid; t < numPos; t += 1024) {
        int i = selPos[t];
        float x = logits[(size_t)b * NB + i];
        bce_acc += fmaxf(x, 0.0f) - x + log1pf(expf(-fabsf(x)));
        float4 a = ((const float4*)anchors)[(size_t)b * NB + i];
        float a1 = (a.z - a.x) * (a.w - a.y);
        float ib = -1.0f, ub = 1.0f;
        int bi = 0;
        #pragma unroll 8
        for (int g = 0; g < GG; ++g) {
            float4 c = sG[g];
            float ga = (c.z - c.x) * (c.w - c.y);
            float w = fmaxf(fminf(a.z, c.z) - fmaxf(a.x, c.x), 0.0f);
            float h = fmaxf(fminf(a.w, c.w) - fmaxf(a.y, c.y), 0.0f);
            float inter = w * h;
            float u = (a1 + ga) - inter;
            bool better = inter * ub > ib * u;
            ib = better ? inter : ib;
            ub = better ? u : ub;
            bi = better ? g : bi;
        }
        float4 t4 = sG[bi];
        float acx = (a.x + a.z) / 2.0f, acy = (a.y + a.w) / 2.0f;
        float aw = a.z - a.x, ah = a.w - a.y;
        float tcx = (t4.x + t4.z) / 2.0f, tcy = (t4.y + t4.w) / 2.0f;
        float tw = t4.z - t4.x, th = t4.w - t4.y;
        float d0 = (tcx - acx) / aw;
        float d1 = (tcy - acy) / ah;
        float d2 = logf(tw / aw);
        float d3 = logf(th / ah);
        float4 r = ((const float4*)breg)[(size_t)b * NB + i];
        float df;
        df = fabsf(r.x - d0); sl1_acc += (df < 1.0f) ? 0.5f * df * df : df - 0.5f;
        df = fabsf(r.y - d1); sl1_acc += (df < 1.0f) ? 0.5f * df * df : df - 0.5f;
        df = fabsf(r.z - d2); sl1_acc += (df < 1.0f) ? 0.5f * df * df : df - 0.5f;
        df = fabsf(r.w - d3); sl1_acc += (df < 1.0f) ? 0.5f * df * df : df - 0.5f;
    }
    for (int t = tid; t < numNeg; t += 1024) {
        int i = selNeg[t];
        float x = logits[(size_t)b * NB + i];
        bce_acc += fmaxf(x, 0.0f) + log1pf(expf(-fabsf(x)));
    }
    for (int off = 32; off > 0; off >>= 1) {
        bce_acc += __shfl_down(bce_acc, off);
        sl1_acc += __shfl_down(sl1_acc, off);
    }
    if (lane == 0) {
        atomicAdd(&sB, bce_acc);
        atomicAdd(&sS, sl1_acc);
    }
    __syncthreads();
    if (tid == 0) {
        partial[b * 4 + 0] = sB;
        partial[b * 4 + 1] = (float)(numPos + numNeg);
        partial[b * 4 + 2] = sS;
        partial[b * 4 + 3] = (float)numPos;
    }

    __threadfence();
    if (tid == 0) ticket = atomicAdd(done, 1u);
    __syncthreads();
    if (ticket != BB - 1) return;
    __threadfence();
    if (tid == 0) {
        float bce = 0.0f, val = 0.0f, sl1 = 0.0f, np = 0.0f;
        #pragma unroll
        for (int w = 0; w < BB; ++w) {
            bce += partial[w * 4 + 0];
            val += partial[w * 4 + 1];
            sl1 += partial[w * 4 + 2];
            np  += partial[w * 4 + 3];
        }
        out[0] = bce / fmaxf(val, 1.0f);
        out[1] = sl1 / fmaxf(np * 4.0f, 1.0f);
    }
}

// ---------------- probe: K2 clone x REPS_K2 (no ticket/out; scratch partial2) ----------------
__global__ __launch_bounds__(1024) void rpn_probe_k2(
        const uint8_t* __restrict__ flags,
        const float* __restrict__ logits, const float* __restrict__ breg,
        const float* __restrict__ anchors, const float* __restrict__ gt,
        const uint32_t* __restrict__ chunkCnt,
        float* __restrict__ partial2) {
    int b = blockIdx.x;
    const uint8_t* __restrict__ F = flags + (size_t)b * NB;
    __shared__ __align__(16) float4 sG[GG];
    __shared__ int basP[NCHP], basN[NCHP];
    __shared__ int sTotP, sTotN;
    __shared__ int selPos[MAXPOS];
    __shared__ int selNeg[BATCH];
    __shared__ float sB, sS;
    int tid = threadIdx.x, lane = tid & 63, wid = tid >> 6;

    if (tid < GG) sG[tid] = ((const float4*)gt)[b * GG + tid];
    __syncthreads();

    for (int r = 0; r < REPS_K2; ++r) {
        if (tid == 0) { sB = 0.0f; sS = 0.0f; }
        if (wid == 0) {
            unsigned long long e = 0ULL;
            if (lane < NCHP) {
                uint32_t c = chunkCnt[b * NCHP + lane];
                e = (unsigned long long)(c & 0xFFFFu) | ((unsigned long long)(c >> 16) << 32);
            }
            unsigned long long inc = e;
            for (int off = 1; off < 64; off <<= 1) {
                unsigned long long v = __shfl_up(inc, off);
                if (lane >= off) inc += v;
            }
            if (lane < NCHP) {
                unsigned long long ex = inc - e;
                basP[lane] = (int)(ex & 0xFFFFFFFFULL);
                basN[lane] = (int)(ex >> 32);
            }
            unsigned long long tot = __shfl(inc, 63);
            if (lane == 0) {
                sTotP = (int)(tot & 0xFFFFFFFFULL);
                sTotN = (int)(tot >> 32);
            }
        }
        __syncthreads();

        bool fast = (sTotP >= MAXPOS) && (sTotN >= BATCH - MAXPOS);
        int numPos = MAXPOS, numNeg = BATCH - MAXPOS;
        if (fast) {
            for (int c = wid; c < NCHP; c += 16) {
                int bp = basP[c], bn = basN[c];
                if (bp >= numPos && bn >= numNeg) break;
                int offP = 0, offN = 0;
                #pragma unroll
                for (int s = 0; s < CHP / 64; ++s) {
                    int idx = c * CHP + s * 64 + lane;
                    uint8_t f = F[idx];
                    bool p = (f & 1) != 0, n = (f & 2) != 0;
                    unsigned long long mpm = __ballot(p), mnm = __ballot(n);
                    unsigned long long lt = (1ULL << lane) - 1ULL;
                    int rp = bp + offP + __popcll(mpm & lt);
                    int rn = bn + offN + __popcll(mnm & lt);
                    if (p && rp < numPos) selPos[rp] = idx;
                    if (n && rn < numNeg) selNeg[rn] = idx;
                    offP += __popcll(mpm); offN += __popcll(mnm);
                }
            }
        }
        __syncthreads();

        float bce_acc = 0.0f, sl1_acc = 0.0f;
        for (int t = tid; t < numPos; t += 1024) {
            int i = selPos[t];
            int il = min(i + (r & 1), NB - 1);   // perturb per rep (defeat LICM)
            float x = logits[(size_t)b * NB + il];
            bce_acc += fmaxf(x, 0.0f) - x + log1pf(expf(-fabsf(x)));
            float4 a = ((const float4*)anchors)[(size_t)b * NB + i];
            float a1 = (a.z - a.x) * (a.w - a.y);
            float ib = -1.0f, ub = 1.0f;
            int bi = 0;
            #pragma unroll 8
            for (int g = 0; g < GG; ++g) {
                float4 c = sG[g];
                float ga = (c.z - c.x) * (c.w - c.y);
                float w = fmaxf(fminf(a.z, c.z) - fmaxf(a.x, c.x), 0.0f);
                float h = fmaxf(fminf(a.w, c.w) - fmaxf(a.y, c.y), 0.0f);
                float inter = w * h;
                float u = (a1 + ga) - inter;
                bool better = inter * ub > ib * u;
                ib = better ? inter : ib;
                ub = better ? u : ub;
                bi = better ? g : bi;
            }
            float4 t4 = sG[bi];
            float acx = (a.x + a.z) / 2.0f, acy = (a.y + a.w) / 2.0f;
            float aw = a.z - a.x, ah = a.w - a.y;
            float tcx = (t4.x + t4.z) / 2.0f, tcy = (t4.y + t4.w) / 2.0f;
            float tw = t4.z - t4.x, th = t4.w - t4.y;
            float d0 = (tcx - acx) / aw;
            float d1 = (tcy - acy) / ah;
            float d2 = logf(tw / aw);
            float d3 = logf(th / ah);
            float4 rr = ((const float4*)breg)[(size_t)b * NB + i];
            float df;
            df = fabsf(rr.x - d0); sl1_acc += (df < 1.0f) ? 0.5f * df * df : df - 0.5f;
            df = fabsf(rr.y - d1); sl1_acc += (df < 1.0f) ? 0.5f * df * df : df - 0.5f;
            df = fabsf(rr.z - d2); sl1_acc += (df < 1.0f) ? 0.5f * df * df : df - 0.5f;
            df = fabsf(rr.w - d3); sl1_acc += (df < 1.0f) ? 0.5f * df * df : df - 0.5f;
        }
        for (int t = tid; t < numNeg; t += 1024) {
            int i = min(selNeg[t] + (r & 1), NB - 1);
            float x = logits[(size_t)b * NB + i];
            bce_acc += fmaxf(x, 0.0f) + log1pf(expf(-fabsf(x)));
        }
        for (int off = 32; off > 0; off >>= 1) {
            bce_acc += __shfl_down(bce_acc, off);
            sl1_acc += __shfl_down(sl1_acc, off);
        }
        if (lane == 0) {
            atomicAdd(&sB, bce_acc);
            atomicAdd(&sS, sl1_acc);
        }
        __syncthreads();
        if (tid == 0) {
            partial2[b * 4 + 0] = sB;
            partial2[b * 4 + 1] = sS;
        }
        __syncthreads();
    }
}

// ---------------- probe: K1 clone x REPS_K1 (perturbed; runs LAST) ----------------
__global__ __launch_bounds__(256) void rpn_probe_k1(
        const float* __restrict__ anchors, const float* __restrict__ gt,
        uint8_t* __restrict__ flags, uint32_t* __restrict__ chunkCnt) {
    int b = blockIdx.y;
    int tid = threadIdx.x, lane = tid & 63, wid = tid >> 6;
    __shared__ __align__(16) float4 sG[GG];
    __shared__ uint32_t wSum[4];
    if (tid < GG) sG[tid] = ((const float4*)gt)[b * GG + tid];
    __syncthreads();
    for (int r = 0; r < REPS_K1; ++r) {
        int i = blockIdx.x * CHP + tid + ((r & 1) << 7);   // < MPRE+128 <= NB
        float4 a = ((const float4*)anchors)[(size_t)b * NB + i];
        float na1 = -((a.z - a.x) * (a.w - a.y));
        float mp = -1.0f, mn = -1.0f;
        #pragma unroll 8
        for (int g = 0; g < GG; ++g) {
            float4 c = sG[g];
            float ga = (c.z - c.x) * (c.w - c.y);
            float w = fmaxf(fminf(a.z, c.z) - fmaxf(a.x, c.x), 0.0f);
            float h = fmaxf(fminf(a.w, c.w) - fmaxf(a.y, c.y), 0.0f);
            float inter = w * h;
            float s = na1 - ga;
            mp = fmaxf(mp, __builtin_fmaf(CP, inter, s));
            mn = fmaxf(mn, __builtin_fmaf(CN, inter, s));
        }
        bool p = (mp >= 0.0f);
        bool n = (mn < 0.0f);
        flags[(size_t)b * NB + i] = (uint8_t)((p ? 1 : 0) | (n ? 2 : 0));
        uint32_t pn = (p ? 1u : 0u) + (n ? 0x10000u : 0u);
        for (int off = 32; off > 0; off >>= 1) pn += __shfl_down(pn, off);
        if (lane == 0) wSum[wid] = pn;
        __syncthreads();
        if (tid == 0)
            chunkCnt[b * NCHP + blockIdx.x] = wSum[0] + wSum[1] + wSum[2] + wSum[3];
        __syncthreads();
    }
}

extern "C" void kernel_launch(void* const* d_in, const int* in_sizes, int n_in,
                              void* d_out, int out_size, void* d_ws, size_t ws_size,
                              hipStream_t stream) {
    const float* cls  = (const float*)d_in[0];  // [B,N,1]
    const float* breg = (const float*)d_in[1];  // [B,N,4]
    const float* anch = (const float*)d_in[2];  // [B,N,4]
    const float* gt   = (const float*)d_in[3];  // [B,G,4]
    float* out = (float*)d_out;

    uint8_t*  flags    = (uint8_t*)d_ws;                            // B*N (prefix used)
    uint32_t* chunkCnt = (uint32_t*)((uint8_t*)d_ws + 800000);      // B*NCHP
    float*    partial  = (float*)(chunkCnt + BB * NCHP);            // 16 floats
    uint32_t* done     = (uint32_t*)(partial + 16);
    float*    partial2 = (float*)(done + 4);                        // probe scratch

    dim3 g1(NCHP, BB);
    // real pipeline (r12 + deterministic done-reset in K1)
    rpn_flags_kernel<<<g1, 256, 0, stream>>>(anch, gt, flags, chunkCnt, done);
    rpn_select_kernel<<<BB, 1024, 0, stream>>>(flags, cls, breg, anch, gt,
                                               chunkCnt, partial, done, out);
    // probes (after consumption; probe_k2 reads pristine flags, probe_k1 clobbers last)
    rpn_probe_k2<<<BB, 1024, 0, stream>>>(flags, cls, breg, anch, gt,
                                          chunkCnt, partial2);
    rpn_probe_k1<<<g1, 256, 0, stream>>>(anch, gt, flags, chunkCnt);
}

// Round 16
// 26.238 us; speedup vs baseline: 8.7349x; 8.7349x over previous
//
#include <hip/hip_runtime.h>
#include <stdint.h>

#define NB 200000
#define BB 4
#define GG 64
#define MAXPOS 128
#define BATCH 256
#define MPRE 16384                 // prefix length scanned by K1 (exactness checked in K2)
#define CHP 256                    // anchors per K1 block / per selection chunk
#define NCHP (MPRE / CHP)          // 64 chunks per image

// thresholds folded: inter - t*u >= 0  <=>  ((1+t)/t)*inter - (a1+ga) >= 0
#define CP (1.7f / 0.7f)
#define CN (1.3f / 0.3f)

// ---------------- K1: prefix flags, 2 threads/anchor (halved GT chain) ----------------
// 512 threads = 256 anchors x 2 halves; half h covers GTs [h*32, h*32+32).
// Merge mp/mn across the (even,odd) lane pair with one shfl_xor.
__global__ __launch_bounds__(512) void rpn_flags_kernel(
        const float* __restrict__ anchors, const float* __restrict__ gt,
        uint8_t* __restrict__ flags, uint32_t* __restrict__ chunkCnt,
        uint32_t* __restrict__ done) {
    int b = blockIdx.y;
    int tid = threadIdx.x, lane = tid & 63, wid = tid >> 6;
    if (blockIdx.x == 0 && b == 0 && tid == 0) *done = 0u;  // deterministic ticket init
    __shared__ __align__(16) float4 sG[GG];
    if (tid < GG) sG[tid] = ((const float4*)gt)[b * GG + tid];
    __syncthreads();

    int i = blockIdx.x * CHP + (tid >> 1);     // i < MPRE <= NB always
    int half = tid & 1;
    float4 a = ((const float4*)anchors)[(size_t)b * NB + i];
    float na1 = -((a.z - a.x) * (a.w - a.y));
    float mp = -1.0f, mn = -1.0f;

    int g0 = half * 32;
    #pragma unroll 8
    for (int g = g0; g < g0 + 32; ++g) {
        float4 c = sG[g];                       // broadcast ds_read_b128
        float ga = (c.z - c.x) * (c.w - c.y);
        float w = fmaxf(fminf(a.z, c.z) - fmaxf(a.x, c.x), 0.0f);
        float h = fmaxf(fminf(a.w, c.w) - fmaxf(a.y, c.y), 0.0f);
        float inter = w * h;
        float s = na1 - ga;
        mp = fmaxf(mp, __builtin_fmaf(CP, inter, s));
        mn = fmaxf(mn, __builtin_fmaf(CN, inter, s));
    }
    // merge the two halves (lanes 2k / 2k+1)
    mp = fmaxf(mp, __shfl_xor(mp, 1));
    mn = fmaxf(mn, __shfl_xor(mn, 1));

    bool even = (half == 0);
    bool p = even && (mp >= 0.0f);
    bool n = even && (mn < 0.0f);
    if (even) flags[(size_t)b * NB + i] = (uint8_t)((p ? 1 : 0) | (n ? 2 : 0));

    uint32_t pn = (p ? 1u : 0u) + (n ? 0x10000u : 0u);
    for (int off = 32; off > 0; off >>= 1) pn += __shfl_down(pn, off);
    __shared__ uint32_t wSum[8];
    if (lane == 0) wSum[wid] = pn;
    __syncthreads();
    if (tid == 0) {
        uint32_t s = 0;
        #pragma unroll
        for (int w = 0; w < 8; ++w) s += wSum[w];
        chunkCnt[b * NCHP + blockIdx.x] = s;
    }
}

// ---------------- K2: scan + selection + loss (8-lane-group argmax) + ticket finalize ----------------
__global__ __launch_bounds__(1024) void rpn_select_kernel(
        const uint8_t* __restrict__ flags,
        const float* __restrict__ logits, const float* __restrict__ breg,
        const float* __restrict__ anchors, const float* __restrict__ gt,
        const uint32_t* __restrict__ chunkCnt,
        float* __restrict__ partial, uint32_t* __restrict__ done,
        float* __restrict__ out) {
    int b = blockIdx.x;
    const uint8_t* __restrict__ F = flags + (size_t)b * NB;
    __shared__ __align__(16) float4 sG[GG];
    __shared__ int basP[NCHP], basN[NCHP];
    __shared__ int sTotP, sTotN, sNumPos, sNumNeg;
    __shared__ int selPos[MAXPOS];
    __shared__ int selNeg[BATCH];
    __shared__ float sB, sS;
    __shared__ uint32_t ticket;
    int tid = threadIdx.x, lane = tid & 63, wid = tid >> 6;

    if (tid < GG) sG[tid] = ((const float4*)gt)[b * GG + tid];
    if (tid == 0) { sB = 0.0f; sS = 0.0f; }

    if (wid == 0) {
        unsigned long long e = 0ULL;
        if (lane < NCHP) {
            uint32_t c = chunkCnt[b * NCHP + lane];
            e = (unsigned long long)(c & 0xFFFFu) | ((unsigned long long)(c >> 16) << 32);
        }
        unsigned long long inc = e;
        for (int off = 1; off < 64; off <<= 1) {
            unsigned long long v = __shfl_up(inc, off);
            if (lane >= off) inc += v;
        }
        if (lane < NCHP) {
            unsigned long long ex = inc - e;
            basP[lane] = (int)(ex & 0xFFFFFFFFULL);
            basN[lane] = (int)(ex >> 32);
        }
        unsigned long long tot = __shfl(inc, 63);
        if (lane == 0) {
            sTotP = (int)(tot & 0xFFFFFFFFULL);
            sTotN = (int)(tot >> 32);
        }
    }
    __syncthreads();

    bool fast = (sTotP >= MAXPOS) && (sTotN >= BATCH - MAXPOS);
    int numPos, numNeg;

    if (fast) {
        numPos = MAXPOS; numNeg = BATCH - MAXPOS;
        for (int c = wid; c < NCHP; c += 16) {
            int bp = basP[c], bn = basN[c];
            if (bp >= numPos && bn >= numNeg) break;
            int offP = 0, offN = 0;
            #pragma unroll
            for (int s = 0; s < CHP / 64; ++s) {
                int idx = c * CHP + s * 64 + lane;
                uint8_t f = F[idx];
                bool p = (f & 1) != 0, n = (f & 2) != 0;
                unsigned long long mpm = __ballot(p), mnm = __ballot(n);
                unsigned long long lt = (1ULL << lane) - 1ULL;
                int rp = bp + offP + __popcll(mpm & lt);
                int rn = bn + offN + __popcll(mnm & lt);
                if (p && rp < numPos) selPos[rp] = idx;
                if (n && rn < numNeg) selNeg[rn] = idx;
                offP += __popcll(mpm); offN += __popcll(mnm);
            }
        }
    } else {
        if (wid == 0) {
            int totP = 0, totN = 0;
            for (int g0 = 0; g0 < NB; g0 += 64) {
                int idx = g0 + lane;
                bool p = false, n = false;
                if (idx < NB) {
                    if (idx < MPRE) {
                        uint8_t f = F[idx];
                        p = (f & 1) != 0; n = (f & 2) != 0;
                    } else {
                        float4 a = ((const float4*)anchors)[(size_t)b * NB + idx];
                        float na1 = -((a.z - a.x) * (a.w - a.y));
                        float mp = -1.0f, mn = -1.0f;
                        for (int g = 0; g < GG; ++g) {
                            float4 c = sG[g];
                            float ga = (c.z - c.x) * (c.w - c.y);
                            float w = fmaxf(fminf(a.z, c.z) - fmaxf(a.x, c.x), 0.0f);
                            float h = fmaxf(fminf(a.w, c.w) - fmaxf(a.y, c.y), 0.0f);
                            float inter = w * h;
                            float s = na1 - ga;
                            mp = fmaxf(mp, __builtin_fmaf(CP, inter, s));
                            mn = fmaxf(mn, __builtin_fmaf(CN, inter, s));
                        }
                        p = (mp >= 0.0f); n = (mn < 0.0f);
                    }
                }
                unsigned long long mpm = __ballot(p), mnm = __ballot(n);
                unsigned long long lt = (1ULL << lane) - 1ULL;
                int rp = totP + __popcll(mpm & lt);
                int rn = totN + __popcll(mnm & lt);
                if (p && rp < MAXPOS) selPos[rp] = idx;
                if (n && rn < BATCH) selNeg[rn] = idx;
                totP += __popcll(mpm); totN += __popcll(mnm);
                if (totP >= MAXPOS && totN >= BATCH) break;
            }
            if (lane == 0) {
                int np = min(totP, MAXPOS);
                sNumPos = np;
                sNumNeg = min(totN, BATCH - np);
            }
        }
    }
    __syncthreads();
    if (!fast) { numPos = sNumPos; numNeg = sNumNeg; }

    // --- loss: positives via 8-lane groups (posIdx = wid*8 + lane>>3, slice = lane&7) ---
    float bce_acc = 0.0f, sl1_acc = 0.0f;
    int posIdx = wid * 8 + (lane >> 3);
    int slice = lane & 7;
    if (posIdx < numPos) {
        int i = selPos[posIdx];
        float4 a = ((const float4*)anchors)[(size_t)b * NB + i];
        float a1 = (a.z - a.x) * (a.w - a.y);
        // 8-GT slice first-max (cross-mult), then 3-step merge with first-max tie rule
        float ib = -1.0f, ub = 1.0f;
        int bi = slice * 8;
        #pragma unroll
        for (int gg = 0; gg < 8; ++gg) {
            int g = slice * 8 + gg;
            float4 c = sG[g];
            float ga = (c.z - c.x) * (c.w - c.y);
            float w = fmaxf(fminf(a.z, c.z) - fmaxf(a.x, c.x), 0.0f);
            float h = fmaxf(fminf(a.w, c.w) - fmaxf(a.y, c.y), 0.0f);
            float inter = w * h;
            float u = (a1 + ga) - inter;
            bool better = inter * ub > ib * u;
            ib = better ? inter : ib;
            ub = better ? u : ub;
            bi = better ? g : bi;
        }
        #pragma unroll
        for (int m = 1; m < 8; m <<= 1) {
            float ib_o = __shfl_xor(ib, m);
            float ub_o = __shfl_xor(ub, m);
            int   bi_o = __shfl_xor(bi, m);
            float l = ib_o * ub, r = ib * ub_o;
            bool take = (l > r) || ((l == r) && (bi_o < bi));  // first-max across slices
            ib = take ? ib_o : ib;
            ub = take ? ub_o : ub;
            bi = take ? bi_o : bi;
        }
        if (slice == 0) {
            float x = logits[(size_t)b * NB + i];
            bce_acc += fmaxf(x, 0.0f) - x + log1pf(expf(-fabsf(x)));
            float4 t4 = sG[bi];
            float acx = (a.x + a.z) / 2.0f, acy = (a.y + a.w) / 2.0f;
            float aw = a.z - a.x, ah = a.w - a.y;
            float tcx = (t4.x + t4.z) / 2.0f, tcy = (t4.y + t4.w) / 2.0f;
            float tw = t4.z - t4.x, th = t4.w - t4.y;
            float d0 = (tcx - acx) / aw;
            float d1 = (tcy - acy) / ah;
            float d2 = logf(tw / aw);
            float d3 = logf(th / ah);
            float4 r4 = ((const float4*)breg)[(size_t)b * NB + i];
            float df;
            df = fabsf(r4.x - d0); sl1_acc += (df < 1.0f) ? 0.5f * df * df : df - 0.5f;
            df = fabsf(r4.y - d1); sl1_acc += (df < 1.0f) ? 0.5f * df * df : df - 0.5f;
            df = fabsf(r4.z - d2); sl1_acc += (df < 1.0f) ? 0.5f * df * df : df - 0.5f;
            df = fabsf(r4.w - d3); sl1_acc += (df < 1.0f) ? 0.5f * df * df : df - 0.5f;
        }
    }
    for (int t = tid; t < numNeg; t += 1024) {
        int i = selNeg[t];
        float x = logits[(size_t)b * NB + i];
        bce_acc += fmaxf(x, 0.0f) + log1pf(expf(-fabsf(x)));
    }
    for (int off = 32; off > 0; off >>= 1) {
        bce_acc += __shfl_down(bce_acc, off);
        sl1_acc += __shfl_down(sl1_acc, off);
    }
    if (lane == 0) {
        atomicAdd(&sB, bce_acc);
        atomicAdd(&sS, sl1_acc);
    }
    __syncthreads();
    if (tid == 0) {
        partial[b * 4 + 0] = sB;
        partial[b * 4 + 1] = (float)(numPos + numNeg);
        partial[b * 4 + 2] = sS;
        partial[b * 4 + 3] = (float)numPos;
    }

    // --- last-block finalize (4 blocks; ticket reset by K1 every call) ---
    __threadfence();
    if (tid == 0) ticket = atomicAdd(done, 1u);
    __syncthreads();
    if (ticket != BB - 1) return;
    __threadfence();
    if (tid == 0) {
        float bce = 0.0f, val = 0.0f, sl1 = 0.0f, np = 0.0f;
        #pragma unroll
        for (int w = 0; w < BB; ++w) {
            bce += partial[w * 4 + 0];
            val += partial[w * 4 + 1];
            sl1 += partial[w * 4 + 2];
            np  += partial[w * 4 + 3];
        }
        out[0] = bce / fmaxf(val, 1.0f);
        out[1] = sl1 / fmaxf(np * 4.0f, 1.0f);
    }
}

extern "C" void kernel_launch(void* const* d_in, const int* in_sizes, int n_in,
                              void* d_out, int out_size, void* d_ws, size_t ws_size,
                              hipStream_t stream) {
    const float* cls  = (const float*)d_in[0];  // [B,N,1]
    const float* breg = (const float*)d_in[1];  // [B,N,4]
    const float* anch = (const float*)d_in[2];  // [B,N,4]
    const float* gt   = (const float*)d_in[3];  // [B,G,4]
    float* out = (float*)d_out;

    uint8_t*  flags    = (uint8_t*)d_ws;                            // B*N (prefix used)
    uint32_t* chunkCnt = (uint32_t*)((uint8_t*)d_ws + 800000);      // B*NCHP
    float*    partial  = (float*)(chunkCnt + BB * NCHP);            // 16 floats
    uint32_t* done     = (uint32_t*)(partial + 16);

    dim3 g1(NCHP, BB);
    rpn_flags_kernel<<<g1, 512, 0, stream>>>(anch, gt, flags, chunkCnt, done);
    rpn_select_kernel<<<BB, 1024, 0, stream>>>(flags, cls, breg, anch, gt,
                                               chunkCnt, partial, done, out);
}